// Round 17
// baseline (877.687 us; speedup 1.0000x reference)
//
#include <hip/hip_runtime.h>
#include <hip/hip_bf16.h>

#define VOCAB 32000
#define EMB   128
#define HID   128
#define BB    8
#define SS    1024

typedef __bf16 bf16x8_t __attribute__((ext_vector_type(8)));
typedef float  f32x4_t  __attribute__((ext_vector_type(4)));

// ---------------------------------------------------------------------------
// Kernel A: xp[b,s,h] = sum_e emb[x[b,s],e] * W_ih[h,e] + b_ih[h] + b_hh[h]
// ---------------------------------------------------------------------------
__global__ __launch_bounds__(512) void xproj_kernel(
    const int* __restrict__ x, const float* __restrict__ emb,
    const float* __restrict__ W_ih, const float* __restrict__ b_ih,
    const float* __restrict__ b_hh, float* __restrict__ xp)
{
    const int t  = threadIdx.x;
    const int h  = t >> 2;
    const int ks = t & 3;

    float w[32];
    {
        const float* wr = W_ih + h * EMB + ks * 32;
        #pragma unroll
        for (int i = 0; i < 32; i += 4) {
            float4 v = *(const float4*)(wr + i);
            w[i] = v.x; w[i+1] = v.y; w[i+2] = v.z; w[i+3] = v.w;
        }
    }
    const float bias = b_ih[h] + b_hh[h];

    __shared__ float el[2][EMB];
    const int base = blockIdx.x * 32;

    float4 v = make_float4(0.f, 0.f, 0.f, 0.f);
    if (t < 32) v = *(const float4*)(emb + (size_t)x[base] * EMB + t * 4);

    for (int r = 0; r < 32; ++r) {
        if (t < 32) *(float4*)(&el[r & 1][t * 4]) = v;
        __syncthreads();
        if (t < 32 && r + 1 < 32)
            v = *(const float4*)(emb + (size_t)x[base + r + 1] * EMB + t * 4);

        float a0 = 0.f, a1 = 0.f, a2 = 0.f, a3 = 0.f;
        const float* e = &el[r & 1][ks * 32];
        #pragma unroll
        for (int c = 0; c < 8; ++c) {
            float4 hv = *(const float4*)(e + c * 4);
            a0 = fmaf(w[c*4+0], hv.x, a0);
            a1 = fmaf(w[c*4+1], hv.y, a1);
            a2 = fmaf(w[c*4+2], hv.z, a2);
            a3 = fmaf(w[c*4+3], hv.w, a3);
        }
        float sum = (a0 + a1) + (a2 + a3);
        sum += __shfl_xor(sum, 1);
        sum += __shfl_xor(sum, 2);
        if (ks == 0) xp[(size_t)(base + r) * HID + h] = bias + sum;
    }
}

// ---------------------------------------------------------------------------
// Kernel D: fp32 -> bf16 convert for fc_W
// ---------------------------------------------------------------------------
__global__ __launch_bounds__(256) void convert_bf16_kernel(
    const float* __restrict__ in, __hip_bfloat16* __restrict__ out)
{
    const size_t i = ((size_t)blockIdx.x * 256 + threadIdx.x) * 8;
    float4 a = *(const float4*)(in + i);
    float4 b = *(const float4*)(in + i + 4);
    union { __hip_bfloat16 h[8]; uint4 u; } p;
    p.h[0] = __float2bfloat16(a.x); p.h[1] = __float2bfloat16(a.y);
    p.h[2] = __float2bfloat16(a.z); p.h[3] = __float2bfloat16(a.w);
    p.h[4] = __float2bfloat16(b.x); p.h[5] = __float2bfloat16(b.y);
    p.h[6] = __float2bfloat16(b.z); p.h[7] = __float2bfloat16(b.w);
    *(uint4*)(out + i) = p.u;
}

// ---------------------------------------------------------------------------
// Mega-kernel, MFMA-batched recurrence:
//   block 0       : RNN producer for ALL 8 batches. Per step, H_new[128x8] =
//                   tanh(XP_t + W_hh @ H) as 32 MFMA 16x16x32 across 4 waves
//                   (wave = 2 row-tiles; A-frags = W_hh bf16 in registers).
//                   H in LDS bf16 [n][k], 272B row pitch (2-way banks, free).
//                   D layout (fc-validated): col(lane&15)=batch, row=j ->
//                   lane finalizes (batch=lr, 4 consecutive j): float4 xp,
//                   uint2 hs store, ds_write_b64 H. One flag/chunk.
//   blocks 1..7   : exit.
//   blocks 8..255 : fc consumers, R13-exact (NC=248), single flag prog[0].
// ---------------------------------------------------------------------------
__global__ __launch_bounds__(256) void mega_kernel(
    const float* __restrict__ xp, const float* __restrict__ W_hh,
    __hip_bfloat16* __restrict__ hs_bf16, float* __restrict__ hidden_out,
    const __hip_bfloat16* __restrict__ Wb, const float* __restrict__ fc_b,
    float* __restrict__ C, unsigned int* __restrict__ prog)
{
    __shared__ __hip_bfloat16 Hb[2][2176];   // [buf][16 rows x 136 pitch]

    const int bid = blockIdx.x;
    const int t   = threadIdx.x;

    if (bid == 0) {
        // ----------------- MFMA RNN producer (all batches) -----------------
        const int wv = t >> 6;           // wave 0..3: m-tiles {2wv, 2wv+1}
        const int l  = t & 63;
        const int lr = l & 15;           // batch n (valid <8) / A row-in-tile
        const int kq = l >> 4;           // k-group
        const int j0 = (wv * 2) * 16 + kq * 4;       // mt=0 rows
        const int j1 = (wv * 2 + 1) * 16 + kq * 4;   // mt=1 rows

        // A-frags: W_hh rows (mi*16+lr), k = kf*32 + kq*8 .. +7, bf16.
        bf16x8_t wf[2][4];
        #pragma unroll
        for (int mt = 0; mt < 2; ++mt) {
            const float* wr = W_hh + (size_t)((wv * 2 + mt) * 16 + lr) * HID + kq * 8;
            #pragma unroll
            for (int kf = 0; kf < 4; ++kf) {
                float4 u0 = *(const float4*)(wr + kf * 32);
                float4 u1 = *(const float4*)(wr + kf * 32 + 4);
                union { __hip_bfloat16 q[8]; bf16x8_t v; } pk;
                pk.q[0] = __float2bfloat16(u0.x); pk.q[1] = __float2bfloat16(u0.y);
                pk.q[2] = __float2bfloat16(u0.z); pk.q[3] = __float2bfloat16(u0.w);
                pk.q[4] = __float2bfloat16(u1.x); pk.q[5] = __float2bfloat16(u1.y);
                pk.q[6] = __float2bfloat16(u1.z); pk.q[7] = __float2bfloat16(u1.w);
                wf[mt][kf] = pk.v;
            }
        }

        {   // zero both H buffers (rows 8..15 stay 0 forever)
            __hip_bfloat16* hb = &Hb[0][0];
            for (int i = t; i < 2 * 2176; i += 256) hb[i] = __float2bfloat16(0.f);
        }

        const float*          xpL = xp      + (size_t)lr * SS * HID;  // valid lr<8
        __hip_bfloat16*       hsL = hs_bf16 + (size_t)lr * SS * HID;
        const int  hoff = lr * 136 + kq * 8;
        const bool act  = (lr < 8);

        float4 xsA[2][2], xsB[2][2];
        if (act) {
            #pragma unroll
            for (int u = 0; u < 2; ++u) {
                xsA[u][0] = *(const float4*)(xpL + (size_t)u * HID + j0);
                xsA[u][1] = *(const float4*)(xpL + (size_t)u * HID + j1);
            }
        }
        __syncthreads();

#define PSTEP(XC, u, stepi)                                                  \
    {                                                                        \
        const __hip_bfloat16* hc = &Hb[(stepi) & 1][0];                      \
        bf16x8_t hf0 = *(const bf16x8_t*)(hc + hoff);                        \
        bf16x8_t hf1 = *(const bf16x8_t*)(hc + hoff + 32);                   \
        bf16x8_t hf2 = *(const bf16x8_t*)(hc + hoff + 64);                   \
        bf16x8_t hf3 = *(const bf16x8_t*)(hc + hoff + 96);                   \
        f32x4_t ac0 = {0.f, 0.f, 0.f, 0.f}, ac1 = ac0;                       \
        ac0 = __builtin_amdgcn_mfma_f32_16x16x32_bf16(wf[0][0], hf0, ac0, 0, 0, 0); \
        ac1 = __builtin_amdgcn_mfma_f32_16x16x32_bf16(wf[1][0], hf0, ac1, 0, 0, 0); \
        ac0 = __builtin_amdgcn_mfma_f32_16x16x32_bf16(wf[0][1], hf1, ac0, 0, 0, 0); \
        ac1 = __builtin_amdgcn_mfma_f32_16x16x32_bf16(wf[1][1], hf1, ac1, 0, 0, 0); \
        ac0 = __builtin_amdgcn_mfma_f32_16x16x32_bf16(wf[0][2], hf2, ac0, 0, 0, 0); \
        ac1 = __builtin_amdgcn_mfma_f32_16x16x32_bf16(wf[1][2], hf2, ac1, 0, 0, 0); \
        ac0 = __builtin_amdgcn_mfma_f32_16x16x32_bf16(wf[0][3], hf3, ac0, 0, 0, 0); \
        ac1 = __builtin_amdgcn_mfma_f32_16x16x32_bf16(wf[1][3], hf3, ac1, 0, 0, 0); \
        if (act) {                                                           \
            const float4 xc0 = XC[u][0], xc1 = XC[u][1];                     \
            float z, ee;                                                     \
            z = xc0.x + ac0[0]; ee = __expf(2.f * z);                        \
            const float h00 = 1.f - 2.f * __builtin_amdgcn_rcpf(ee + 1.f);   \
            z = xc0.y + ac0[1]; ee = __expf(2.f * z);                        \
            const float h01 = 1.f - 2.f * __builtin_amdgcn_rcpf(ee + 1.f);   \
            z = xc0.z + ac0[2]; ee = __expf(2.f * z);                        \
            const float h02 = 1.f - 2.f * __builtin_amdgcn_rcpf(ee + 1.f);   \
            z = xc0.w + ac0[3]; ee = __expf(2.f * z);                        \
            const float h03 = 1.f - 2.f * __builtin_amdgcn_rcpf(ee + 1.f);   \
            z = xc1.x + ac1[0]; ee = __expf(2.f * z);                        \
            const float h10 = 1.f - 2.f * __builtin_amdgcn_rcpf(ee + 1.f);   \
            z = xc1.y + ac1[1]; ee = __expf(2.f * z);                        \
            const float h11 = 1.f - 2.f * __builtin_amdgcn_rcpf(ee + 1.f);   \
            z = xc1.z + ac1[2]; ee = __expf(2.f * z);                        \
            const float h12 = 1.f - 2.f * __builtin_amdgcn_rcpf(ee + 1.f);   \
            z = xc1.w + ac1[3]; ee = __expf(2.f * z);                        \
            const float h13 = 1.f - 2.f * __builtin_amdgcn_rcpf(ee + 1.f);   \
            union { __hip_bfloat16 q[4]; uint2 u2; } p0, p1;                 \
            p0.q[0] = __float2bfloat16(h00); p0.q[1] = __float2bfloat16(h01);\
            p0.q[2] = __float2bfloat16(h02); p0.q[3] = __float2bfloat16(h03);\
            p1.q[0] = __float2bfloat16(h10); p1.q[1] = __float2bfloat16(h11);\
            p1.q[2] = __float2bfloat16(h12); p1.q[3] = __float2bfloat16(h13);\
            *(uint2*)(&Hb[((stepi) + 1) & 1][lr * 136 + j0]) = p0.u2;        \
            *(uint2*)(&Hb[((stepi) + 1) & 1][lr * 136 + j1]) = p1.u2;        \
            *(uint2*)(hsL + (size_t)(stepi) * HID + j0) = p0.u2;             \
            *(uint2*)(hsL + (size_t)(stepi) * HID + j1) = p1.u2;             \
            if ((stepi) == SS - 1) {                                         \
                *(float4*)(hidden_out + lr * HID + j0) =                     \
                    make_float4(h00, h01, h02, h03);                         \
                *(float4*)(hidden_out + lr * HID + j1) =                     \
                    make_float4(h10, h11, h12, h13);                         \
            }                                                                \
        }                                                                    \
        asm volatile("s_waitcnt lgkmcnt(0)" ::: "memory");                   \
        __builtin_amdgcn_s_barrier();                                        \
    }

#define SUPER2(XC, XN, BASE)                                                 \
    {                                                                        \
        if (act && (BASE) + 3 < SS) {                                        \
            _Pragma("unroll")                                                \
            for (int u = 0; u < 2; ++u) {                                    \
                XN[u][0] = *(const float4*)(xpL + (size_t)((BASE) + 2 + u) * HID + j0); \
                XN[u][1] = *(const float4*)(xpL + (size_t)((BASE) + 2 + u) * HID + j1); \
            }                                                                \
        }                                                                    \
        PSTEP(XC, 0, (BASE))                                                 \
        PSTEP(XC, 1, (BASE) + 1)                                             \
    }

        for (int chunk = 0; chunk < 8; ++chunk) {
            for (int sb = 0; sb < 32; ++sb) {
                const int base = chunk * 128 + sb * 4;
                SUPER2(xsA, xsB, base);
                SUPER2(xsB, xsA, base + 2);
            }
            // chunk done: drain hs stores, then release the single flag.
            asm volatile("s_waitcnt vmcnt(0)" ::: "memory");
            __builtin_amdgcn_s_barrier();
            if (t == 0)
                __hip_atomic_store(&prog[0], (unsigned)(chunk + 1),
                                   __ATOMIC_RELEASE, __HIP_MEMORY_SCOPE_AGENT);
        }
#undef SUPER2
#undef PSTEP
    } else if (bid >= BB) {
        // ----------------- FC consumer (R13-exact, single flag) -----------
        const int cid  = bid - BB;          // 0..247
        const int NC   = 256 - BB;          // 248
        const int lane = t & 63;
        const int cw   = t >> 6;
        const int wm   = cw >> 1;
        const int wn   = cw & 1;
        const int lr   = lane & 15;
        const int kq   = lane >> 4;

        for (int tc = 0; tc < 8; ++tc) {
            if (t == 0) {
                // RELAXED memory-side RMW poll: fresh value, no cache inv.
                while (__hip_atomic_fetch_add(&prog[0], 0u,
                           __ATOMIC_RELAXED, __HIP_MEMORY_SCOPE_AGENT)
                       < (unsigned)(tc + 1))
                    __builtin_amdgcn_s_sleep(32);
            }
            __syncthreads();
            // ONE acquire fence per chunk: invalidate stale L1/L2 once.
            __builtin_amdgcn_fence(__ATOMIC_ACQUIRE, "agent");

            for (int i = cid; i < 2000; i += NC) {
                const int b2 = i / 250;
                const int nb = i % 250;
                const int mb = b2 * 8 + tc;
                const int m0 = mb * 128 + wm * 64;
                const int n0 = nb * 128 + wn * 64;

                const __hip_bfloat16* Arow = hs_bf16 + (size_t)(m0 + lr) * HID + kq * 8;
                const __hip_bfloat16* Wrow = Wb      + (size_t)(n0 + lr) * HID + kq * 8;

                f32x4_t acc[4][4];
                #pragma unroll
                for (int ii = 0; ii < 4; ++ii)
                    #pragma unroll
                    for (int jj = 0; jj < 4; ++jj)
                        acc[ii][jj] = (f32x4_t){0.f, 0.f, 0.f, 0.f};

                bf16x8_t af[2][4], bw[2][4];
                #pragma unroll
                for (int mt = 0; mt < 4; ++mt)
                    af[0][mt] = *(const bf16x8_t*)(Arow + mt * 16 * HID);
                #pragma unroll
                for (int nt = 0; nt < 4; ++nt)
                    bw[0][nt] = *(const bf16x8_t*)(Wrow + nt * 16 * HID);

                #pragma unroll
                for (int kk = 0; kk < 4; ++kk) {
                    const int cur = kk & 1, nxt = cur ^ 1;
                    if (kk < 3) {
                        const int off = (kk + 1) * 32;
                        #pragma unroll
                        for (int mt = 0; mt < 4; ++mt)
                            af[nxt][mt] = *(const bf16x8_t*)(Arow + mt * 16 * HID + off);
                        #pragma unroll
                        for (int nt = 0; nt < 4; ++nt)
                            bw[nxt][nt] = *(const bf16x8_t*)(Wrow + nt * 16 * HID + off);
                    }
                    #pragma unroll
                    for (int mt = 0; mt < 4; ++mt)
                        #pragma unroll
                        for (int nt = 0; nt < 4; ++nt)
                            acc[mt][nt] = __builtin_amdgcn_mfma_f32_16x16x32_bf16(
                                bw[cur][nt], af[cur][mt], acc[mt][nt], 0, 0, 0);
                }

                // D (swapped): reg axis = 4 consecutive vocab cols, lane&15 = m row
                const int vq = kq * 4;
                #pragma unroll
                for (int nt = 0; nt < 4; ++nt) {
                    const int v0 = n0 + nt * 16 + vq;
                    float4 fb = *(const float4*)(fc_b + v0);
                    const f32x4_t fbv = {fb.x, fb.y, fb.z, fb.w};
                    #pragma unroll
                    for (int mt = 0; mt < 4; ++mt) {
                        const int row = m0 + mt * 16 + lr;
                        *(f32x4_t*)(C + (size_t)row * VOCAB + v0) = acc[mt][nt] + fbv;
                    }
                }
            }
        }
    }
}

// ---------------------------------------------------------------------------
extern "C" void kernel_launch(void* const* d_in, const int* in_sizes, int n_in,
                              void* d_out, int out_size, void* d_ws, size_t ws_size,
                              hipStream_t stream)
{
    const int*   x    = (const int*)  d_in[0];
    const float* emb  = (const float*)d_in[1];
    const float* W_ih = (const float*)d_in[2];
    const float* b_ih = (const float*)d_in[3];
    const float* W_hh = (const float*)d_in[4];
    const float* b_hh = (const float*)d_in[5];
    const float* fc_W = (const float*)d_in[6];
    const float* fc_b = (const float*)d_in[7];

    float* logits = (float*)d_out;
    float* hidden = logits + (size_t)BB * SS * VOCAB;

    char* ws = (char*)d_ws;
    float*           xpb = (float*)ws;                               // 4,194,304 B
    __hip_bfloat16*  hsb = (__hip_bfloat16*)(ws + 4194304);          // 2,097,152 B
    __hip_bfloat16*  fwb = (__hip_bfloat16*)(ws + 6291456);          // 8,192,000 B
    unsigned int*    prg = (unsigned int*)(ws + 14483456);           // 64 B

    hipMemsetAsync(prg, 0, 1024, stream);
    xproj_kernel<<<dim3(256), dim3(512), 0, stream>>>(x, emb, W_ih, b_ih, b_hh, xpb);
    convert_bf16_kernel<<<dim3(2000), dim3(256), 0, stream>>>(fc_W, fwb);
    mega_kernel<<<dim3(256), dim3(256), 0, stream>>>(xpb, W_hh, hsb, hidden,
                                                     fwb, fc_b, logits, prg);
}

// Round 18
// 566.427 us; speedup vs baseline: 1.5495x; 1.5495x over previous
//
#include <hip/hip_runtime.h>
#include <hip/hip_bf16.h>

#define VOCAB 32000
#define EMB   128
#define HID   128
#define BB    8
#define SS    1024

typedef __bf16 bf16x8_t __attribute__((ext_vector_type(8)));
typedef float  f32x4_t  __attribute__((ext_vector_type(4)));

__device__ __forceinline__ float dpp_xor1(float x) {
    return __int_as_float(__builtin_amdgcn_update_dpp(
        0, __float_as_int(x), 0xB1, 0xF, 0xF, true));   // quad_perm(1,0,3,2)
}
__device__ __forceinline__ float dpp_xor2(float x) {
    return __int_as_float(__builtin_amdgcn_update_dpp(
        0, __float_as_int(x), 0x4E, 0xF, 0xF, true));   // quad_perm(2,3,0,1)
}

// ---------------------------------------------------------------------------
// Kernel A: xp[b,s,h] = sum_e emb[x[b,s],e] * W_ih[h,e] + b_ih[h] + b_hh[h]
// ---------------------------------------------------------------------------
__global__ __launch_bounds__(512) void xproj_kernel(
    const int* __restrict__ x, const float* __restrict__ emb,
    const float* __restrict__ W_ih, const float* __restrict__ b_ih,
    const float* __restrict__ b_hh, float* __restrict__ xp)
{
    const int t  = threadIdx.x;
    const int h  = t >> 2;
    const int ks = t & 3;

    float w[32];
    {
        const float* wr = W_ih + h * EMB + ks * 32;
        #pragma unroll
        for (int i = 0; i < 32; i += 4) {
            float4 v = *(const float4*)(wr + i);
            w[i] = v.x; w[i+1] = v.y; w[i+2] = v.z; w[i+3] = v.w;
        }
    }
    const float bias = b_ih[h] + b_hh[h];

    __shared__ float el[2][EMB];
    const int base = blockIdx.x * 32;

    float4 v = make_float4(0.f, 0.f, 0.f, 0.f);
    if (t < 32) v = *(const float4*)(emb + (size_t)x[base] * EMB + t * 4);

    for (int r = 0; r < 32; ++r) {
        if (t < 32) *(float4*)(&el[r & 1][t * 4]) = v;
        __syncthreads();
        if (t < 32 && r + 1 < 32)
            v = *(const float4*)(emb + (size_t)x[base + r + 1] * EMB + t * 4);

        float a0 = 0.f, a1 = 0.f, a2 = 0.f, a3 = 0.f;
        const float* e = &el[r & 1][ks * 32];
        #pragma unroll
        for (int c = 0; c < 8; ++c) {
            float4 hv = *(const float4*)(e + c * 4);
            a0 = fmaf(w[c*4+0], hv.x, a0);
            a1 = fmaf(w[c*4+1], hv.y, a1);
            a2 = fmaf(w[c*4+2], hv.z, a2);
            a3 = fmaf(w[c*4+3], hv.w, a3);
        }
        float sum = (a0 + a1) + (a2 + a3);
        sum += __shfl_xor(sum, 1);
        sum += __shfl_xor(sum, 2);
        if (ks == 0) xp[(size_t)(base + r) * HID + h] = bias + sum;
    }
}

// ---------------------------------------------------------------------------
// Kernel D: fp32 -> bf16 convert for fc_W
// ---------------------------------------------------------------------------
__global__ __launch_bounds__(256) void convert_bf16_kernel(
    const float* __restrict__ in, __hip_bfloat16* __restrict__ out)
{
    const size_t i = ((size_t)blockIdx.x * 256 + threadIdx.x) * 8;
    float4 a = *(const float4*)(in + i);
    float4 b = *(const float4*)(in + i + 4);
    union { __hip_bfloat16 h[8]; uint4 u; } p;
    p.h[0] = __float2bfloat16(a.x); p.h[1] = __float2bfloat16(a.y);
    p.h[2] = __float2bfloat16(a.z); p.h[3] = __float2bfloat16(a.w);
    p.h[4] = __float2bfloat16(b.x); p.h[5] = __float2bfloat16(b.y);
    p.h[6] = __float2bfloat16(b.z); p.h[7] = __float2bfloat16(b.w);
    *(uint4*)(out + i) = p.u;
}

// ---------------------------------------------------------------------------
// Mega-kernel (R13 structure + DEFERRED-STORE producer superstep):
//   blocks 0..7   : RNN producer. Superstep order is now
//                   [issue 16 xp loads][8 steps: compute + LDS only, pack hs
//                   into registers][issue 16 hs stores]. Stores thus leave
//                   the vmcnt chain that gates xp-register consumption
//                   (in-order vmcnt: interleaved fresh-line stores were
//                   adding ~300cyc/step of drain waits).
//   blocks 8..255 : fc consumers, R13-exact (NC=248, poll all 8 padded
//                   flags RELAXED memory-side, ONE acquire fence per tc).
// ---------------------------------------------------------------------------
__global__ __launch_bounds__(256) void mega_kernel(
    const float* __restrict__ xp, const float* __restrict__ W_hh,
    __hip_bfloat16* __restrict__ hs_bf16, float* __restrict__ hidden_out,
    const __hip_bfloat16* __restrict__ Wb, const float* __restrict__ fc_b,
    float* __restrict__ C, unsigned int* __restrict__ prog)
{
    const int bid = blockIdx.x;

    if (bid < BB) {
        // ----------------- RNN producer (batch = bid) -----------------
        const int b  = bid;
        const int t  = threadIdx.x;
        const int w  = t >> 6;
        const int l  = t & 63;
        const int ks = l & 3;
        const int g  = l >> 2;
        const int jb = w * 16 + g;

        f32x4_t wr[2][8];
        #pragma unroll
        for (int m = 0; m < 2; ++m) {
            const float* src = W_hh + (size_t)(jb + 64 * m) * HID + ks * 32;
            #pragma unroll
            for (int i = 0; i < 8; ++i) wr[m][i] = *(const f32x4_t*)(src + i * 4);
        }

        __shared__ float hbuf[2][160];        // padded: word(k) = k + (k>>4)*4
        if (t < 160) hbuf[0][t] = 0.f;

        const float* xpb = xp + (size_t)b * SS * HID;
        const bool  wrt  = (ks == 0);
        const int rbase = ks * 40;

        float xsA[8][2], xsB[8][2];
        if (wrt) {
            #pragma unroll
            for (int u = 0; u < 8; ++u) {
                xsA[u][0] = xpb[(size_t)u * HID + jb];
                xsA[u][1] = xpb[(size_t)u * HID + jb + 64];
            }
        }
        __syncthreads();

// Deferred-store superstep: loads first, compute+LDS in the middle (hs values
// packed into uint2 registers), ALL global stores issued at the end.
#define RNN_SUPERSTEP(XC, XN, BASE)                                          \
    {                                                                        \
        const int nbase_ = (BASE) + 8;                                       \
        if (wrt && nbase_ < SS) {                                            \
            _Pragma("unroll")                                                \
            for (int u = 0; u < 8; ++u) {                                    \
                XN[u][0] = xpb[(size_t)(nbase_ + u) * HID + jb];             \
                XN[u][1] = xpb[(size_t)(nbase_ + u) * HID + jb + 64];        \
            }                                                                \
        }                                                                    \
        uint2 hsv[8];                                                        \
        float hlast0 = 0.f, hlast1 = 0.f;                                    \
        _Pragma("unroll")                                                    \
        for (int u = 0; u < 8; ++u) {                                        \
            const float* hc_ = hbuf[u & 1];                                  \
            f32x4_t hv[8];                                                   \
            _Pragma("unroll")                                                \
            for (int i = 0; i < 4; ++i)                                      \
                hv[i] = *(const f32x4_t*)(hc_ + rbase + i * 4);              \
            _Pragma("unroll")                                                \
            for (int i = 4; i < 8; ++i)                                      \
                hv[i] = *(const f32x4_t*)(hc_ + rbase + 4 + i * 4);          \
            f32x4_t a0 = {0.f,0.f,0.f,0.f}, a1 = a0, c0 = a0, c1 = a0;       \
            _Pragma("unroll")                                                \
            for (int i = 0; i < 4; ++i) {                                    \
                a0 += wr[0][i]   * hv[i];                                    \
                a1 += wr[0][i+4] * hv[i+4];                                  \
                c0 += wr[1][i]   * hv[i];                                    \
                c1 += wr[1][i+4] * hv[i+4];                                  \
            }                                                                \
            f32x4_t av = a0 + a1, cv = c0 + c1;                              \
            float s0 = (av.x + av.y) + (av.z + av.w);                        \
            float s1 = (cv.x + cv.y) + (cv.z + cv.w);                        \
            s0 += dpp_xor1(s0);  s0 += dpp_xor2(s0);                         \
            s1 += dpp_xor1(s1);  s1 += dpp_xor2(s1);                         \
            if (wrt) {                                                       \
                const float z0 = XC[u][0] + s0;                              \
                const float e0 = __expf(2.0f * z0);                          \
                const float h0 = 1.0f - 2.0f * __builtin_amdgcn_rcpf(e0 + 1.0f); \
                const float z1 = XC[u][1] + s1;                              \
                const float e1 = __expf(2.0f * z1);                          \
                const float h1 = 1.0f - 2.0f * __builtin_amdgcn_rcpf(e1 + 1.0f); \
                const int j0 = jb, j1 = jb + 64;                             \
                hbuf[(u + 1) & 1][j0 + ((j0 >> 4) << 2)] = h0;               \
                hbuf[(u + 1) & 1][j1 + ((j1 >> 4) << 2)] = h1;               \
                union { __hip_bfloat16 q[2]; uint2 u2; } pk;                 \
                pk.q[0] = __float2bfloat16(h0);                              \
                pk.q[1] = __float2bfloat16(h1);                              \
                pk.u2.y = pk.u2.x;                                           \
                hsv[u].x = pk.u2.x; hsv[u].y = pk.u2.x;                      \
                hsv[u] = pk.u2;                                              \
                hlast0 = h0; hlast1 = h1;                                    \
            }                                                                \
            asm volatile("s_waitcnt lgkmcnt(0)" ::: "memory");               \
            __builtin_amdgcn_s_barrier();                                    \
        }                                                                    \
        if (wrt) {                                                           \
            _Pragma("unroll")                                                \
            for (int u = 0; u < 8; ++u) {                                    \
                union { uint2 u2; __hip_bfloat16 q[2]; } pk;                 \
                pk.u2 = hsv[u];                                              \
                hs_bf16[((size_t)b * SS + (BASE) + u) * HID + jb]      = pk.q[0]; \
                hs_bf16[((size_t)b * SS + (BASE) + u) * HID + jb + 64] = pk.q[1]; \
            }                                                                \
            if ((BASE) + 8 == SS) {                                          \
                hidden_out[b * HID + jb]      = hlast0;                      \
                hidden_out[b * HID + jb + 64] = hlast1;                      \
            }                                                                \
        }                                                                    \
    }

        for (int chunk = 0; chunk < 8; ++chunk) {
            for (int sb2 = 0; sb2 < 8; ++sb2) {
                const int base = chunk * 128 + sb2 * 16;
                RNN_SUPERSTEP(xsA, xsB, base);
                RNN_SUPERSTEP(xsB, xsA, base + 8);
            }
            // chunk done: drain hs stores, then release the flag (64B-padded).
            asm volatile("s_waitcnt vmcnt(0)" ::: "memory");
            __builtin_amdgcn_s_barrier();
            if (t == 0)
                __hip_atomic_store(&prog[b * 16], (unsigned)(chunk + 1),
                                   __ATOMIC_RELEASE, __HIP_MEMORY_SCOPE_AGENT);
        }
#undef RNN_SUPERSTEP
    } else {
        // ----------------- FC consumer (R13-exact) -----------------
        const int cid  = bid - BB;          // 0..247
        const int NC   = 256 - BB;          // 248
        const int t    = threadIdx.x;
        const int lane = t & 63;
        const int cw   = t >> 6;
        const int wm   = cw >> 1;
        const int wn   = cw & 1;
        const int lr   = lane & 15;
        const int kq   = lane >> 4;

        for (int tc = 0; tc < 8; ++tc) {
            if (t == 0) {
                for (int b2 = 0; b2 < BB; ++b2) {
                    // RELAXED memory-side RMW poll: fresh value, no cache inv.
                    while (__hip_atomic_fetch_add(&prog[b2 * 16], 0u,
                               __ATOMIC_RELAXED, __HIP_MEMORY_SCOPE_AGENT)
                           < (unsigned)(tc + 1))
                        __builtin_amdgcn_s_sleep(32);
                }
            }
            __syncthreads();
            // ONE acquire fence per chunk: invalidate stale L1/L2 once.
            __builtin_amdgcn_fence(__ATOMIC_ACQUIRE, "agent");

            for (int i = cid; i < 2000; i += NC) {
                const int b2 = i / 250;
                const int nb = i % 250;
                const int mb = b2 * 8 + tc;
                const int m0 = mb * 128 + wm * 64;
                const int n0 = nb * 128 + wn * 64;

                const __hip_bfloat16* Arow = hs_bf16 + (size_t)(m0 + lr) * HID + kq * 8;
                const __hip_bfloat16* Wrow = Wb      + (size_t)(n0 + lr) * HID + kq * 8;

                f32x4_t acc[4][4];
                #pragma unroll
                for (int ii = 0; ii < 4; ++ii)
                    #pragma unroll
                    for (int jj = 0; jj < 4; ++jj)
                        acc[ii][jj] = (f32x4_t){0.f, 0.f, 0.f, 0.f};

                bf16x8_t af[2][4], bw[2][4];
                #pragma unroll
                for (int mt = 0; mt < 4; ++mt)
                    af[0][mt] = *(const bf16x8_t*)(Arow + mt * 16 * HID);
                #pragma unroll
                for (int nt = 0; nt < 4; ++nt)
                    bw[0][nt] = *(const bf16x8_t*)(Wrow + nt * 16 * HID);

                #pragma unroll
                for (int kk = 0; kk < 4; ++kk) {
                    const int cur = kk & 1, nxt = cur ^ 1;
                    if (kk < 3) {
                        const int off = (kk + 1) * 32;
                        #pragma unroll
                        for (int mt = 0; mt < 4; ++mt)
                            af[nxt][mt] = *(const bf16x8_t*)(Arow + mt * 16 * HID + off);
                        #pragma unroll
                        for (int nt = 0; nt < 4; ++nt)
                            bw[nxt][nt] = *(const bf16x8_t*)(Wrow + nt * 16 * HID + off);
                    }
                    #pragma unroll
                    for (int mt = 0; mt < 4; ++mt)
                        #pragma unroll
                        for (int nt = 0; nt < 4; ++nt)
                            acc[mt][nt] = __builtin_amdgcn_mfma_f32_16x16x32_bf16(
                                bw[cur][nt], af[cur][mt], acc[mt][nt], 0, 0, 0);
                }

                // D (swapped): reg axis = 4 consecutive vocab cols, lane&15 = m row
                const int vq = kq * 4;
                #pragma unroll
                for (int nt = 0; nt < 4; ++nt) {
                    const int v0 = n0 + nt * 16 + vq;
                    float4 fb = *(const float4*)(fc_b + v0);
                    const f32x4_t fbv = {fb.x, fb.y, fb.z, fb.w};
                    #pragma unroll
                    for (int mt = 0; mt < 4; ++mt) {
                        const int row = m0 + mt * 16 + lr;
                        *(f32x4_t*)(C + (size_t)row * VOCAB + v0) = acc[mt][nt] + fbv;
                    }
                }
            }
        }
    }
}

// ---------------------------------------------------------------------------
extern "C" void kernel_launch(void* const* d_in, const int* in_sizes, int n_in,
                              void* d_out, int out_size, void* d_ws, size_t ws_size,
                              hipStream_t stream)
{
    const int*   x    = (const int*)  d_in[0];
    const float* emb  = (const float*)d_in[1];
    const float* W_ih = (const float*)d_in[2];
    const float* b_ih = (const float*)d_in[3];
    const float* W_hh = (const float*)d_in[4];
    const float* b_hh = (const float*)d_in[5];
    const float* fc_W = (const float*)d_in[6];
    const float* fc_b = (const float*)d_in[7];

    float* logits = (float*)d_out;
    float* hidden = logits + (size_t)BB * SS * VOCAB;

    char* ws = (char*)d_ws;
    float*           xpb = (float*)ws;                               // 4,194,304 B
    __hip_bfloat16*  hsb = (__hip_bfloat16*)(ws + 4194304);          // 2,097,152 B
    __hip_bfloat16*  fwb = (__hip_bfloat16*)(ws + 6291456);          // 8,192,000 B
    unsigned int*    prg = (unsigned int*)(ws + 14483456);           // 8 x 64 B

    hipMemsetAsync(prg, 0, 1024, stream);
    xproj_kernel<<<dim3(256), dim3(512), 0, stream>>>(x, emb, W_ih, b_ih, b_hh, xpb);
    convert_bf16_kernel<<<dim3(2000), dim3(256), 0, stream>>>(fc_W, fwb);
    mega_kernel<<<dim3(256), dim3(256), 0, stream>>>(xpb, W_hh, hsb, hidden,
                                                     fwb, fc_b, logits, prg);
}